// Round 3
// baseline (510.029 us; speedup 1.0000x reference)
//
#include <hip/hip_runtime.h>

#define B_ 64
#define T_ 512
#define F_ 1024
#define U_ 64

// ---------------------------------------------------------------------------
// Kernel 1: potentials[n][u] = x[n][:] . kernel[:][u] + bias[u] (+ boundaries)
// 32768 rows x 64 cols, 2 rows x 4 cols per thread, 1024 blocks (4/CU,
// 4 waves/SIMD). NEW: 2-stage register double-buffer (ping-pong named bufs,
// compile-time indexed) so iteration i+1's 12 float4 loads are in flight
// while iteration i's 64 FMAs issue. FMA order over f identical to the
// validated kernel (ascending f, sequential fmaf per output).
// ---------------------------------------------------------------------------
__global__ __launch_bounds__(256, 4) void crf_gemm_kernel(
    const float* __restrict__ x, const float* __restrict__ w,
    const float* __restrict__ bias, const float* __restrict__ lb,
    const float* __restrict__ rb, float* __restrict__ pot)
{
    const int tid = threadIdx.x;
    const int rt = tid >> 4;        // 16 row-groups x 2 rows
    const int ut = tid & 15;        // 16 col-groups x 4 cols
    const int n0 = blockIdx.x * 32;
    const int r0 = rt * 2;
    const int u0 = ut * 4;

    float acc0[4] = {0.f, 0.f, 0.f, 0.f};
    float acc1[4] = {0.f, 0.f, 0.f, 0.f};

    const float* xp = x + (size_t)(n0 + r0) * F_;
    const float* wp = w + u0;

    float4 xA[4], wA[8], xB[4], wB[8];

    auto LDX = [&](float4* d, int it) {
        const float* p = xp + it * 8;
        d[0] = *reinterpret_cast<const float4*>(p);
        d[1] = *reinterpret_cast<const float4*>(p + 4);
        d[2] = *reinterpret_cast<const float4*>(p + F_);
        d[3] = *reinterpret_cast<const float4*>(p + F_ + 4);
    };
    auto LDW = [&](float4* d, int it) {
        const float* p = wp + (size_t)it * 8 * U_;
#pragma unroll
        for (int ff = 0; ff < 8; ++ff)
            d[ff] = *reinterpret_cast<const float4*>(p + (size_t)ff * U_);
    };
    auto FMA = [&](const float4* xv, const float4* wv) {
        const float xr0[8] = {xv[0].x, xv[0].y, xv[0].z, xv[0].w,
                              xv[1].x, xv[1].y, xv[1].z, xv[1].w};
        const float xr1[8] = {xv[2].x, xv[2].y, xv[2].z, xv[2].w,
                              xv[3].x, xv[3].y, xv[3].z, xv[3].w};
#pragma unroll
        for (int ff = 0; ff < 8; ++ff) {
            acc0[0] = fmaf(xr0[ff], wv[ff].x, acc0[0]);
            acc0[1] = fmaf(xr0[ff], wv[ff].y, acc0[1]);
            acc0[2] = fmaf(xr0[ff], wv[ff].z, acc0[2]);
            acc0[3] = fmaf(xr0[ff], wv[ff].w, acc0[3]);
            acc1[0] = fmaf(xr1[ff], wv[ff].x, acc1[0]);
            acc1[1] = fmaf(xr1[ff], wv[ff].y, acc1[1]);
            acc1[2] = fmaf(xr1[ff], wv[ff].z, acc1[2]);
            acc1[3] = fmaf(xr1[ff], wv[ff].w, acc1[3]);
        }
    };

    LDX(xA, 0); LDW(wA, 0);
    for (int it = 0; it < F_ / 8; it += 2) {
        LDX(xB, it + 1); LDW(wB, it + 1);          // it+1 <= 127: in range
        FMA(xA, wA);
        const int itn = (it + 2 < F_ / 8) ? it + 2 : 0;  // clamp: no OOB
        LDX(xA, itn); LDW(wA, itn);
        FMA(xB, wB);
    }

    const int t0 = n0 & (T_ - 1);   // 32 | 512: block never crosses a batch
    const float4 bs4 = *reinterpret_cast<const float4*>(bias + u0);
    const float4 lb4 = *reinterpret_cast<const float4*>(lb + u0);
    const float4 rb4 = *reinterpret_cast<const float4*>(rb + u0);

#pragma unroll
    for (int i = 0; i < 2; ++i) {
        const float* a = (i == 0) ? acc0 : acc1;
        const int n = n0 + r0 + i;
        const int t = t0 + r0 + i;
        float4 o;
        o.x = a[0] + bs4.x;
        o.y = a[1] + bs4.y;
        o.z = a[2] + bs4.z;
        o.w = a[3] + bs4.w;
        if (t == 0)      { o.x += lb4.x; o.y += lb4.y; o.z += lb4.z; o.w += lb4.w; }
        if (t == T_ - 1) { o.x += rb4.x; o.y += rb4.y; o.z += rb4.z; o.w += rb4.w; }
        *reinterpret_cast<float4*>(pot + (size_t)n * U_ + u0) = o;
    }
}

// ---------------------------------------------------------------------------
// Kernel 2: Viterbi forward + backtrace, one block (4 waves) per batch.
// Thread (wave, lane): output u = wave*16 + (lane>>2), v-chunk vc = lane&3
// covering v in [vc*16, vc*16+16). The 4 partials for a u sit in adjacent
// lanes -> combined with a 2-stage shfl_xor butterfly, lexicographic
// (val, idx) tie-break == jnp.argmax first occurrence. Alpha double-buffered
// in LDS -> ONE barrier per step. Exact reference arithmetic:
// s = (alpha[v] + chain[v][u]) + pot[t][u], strict >, ascending v.
// Backtrace: 2-pass segmented (per-wave composed maps, then 4 parallel
// 128-deep chases) -- integer-exact replica of the sequential chase.
// ---------------------------------------------------------------------------
__global__ __launch_bounds__(256) void crf_viterbi_kernel(
    const float* __restrict__ pot, const float* __restrict__ chain,
    int* __restrict__ path)
{
    const int b = blockIdx.x;
    const int tid = threadIdx.x;
    const int lane = tid & 63;
    const int wv = tid >> 6;              // wave 0..3
    const int u = wv * 16 + (lane >> 2);  // output tag this lane serves
    const int vc = lane & 3;              // v-chunk 0..3

    __shared__ __align__(16) float albuf[2][64];
    __shared__ unsigned char bp[T_ - 1][64];   // 32704 B
    __shared__ unsigned char cmap[4][64];
    __shared__ int es[4];

    float chain_r[16];
#pragma unroll
    for (int k = 0; k < 16; ++k)
        chain_r[k] = chain[(size_t)(vc * 16 + k) * U_ + u];

    const float* potb = pot + (size_t)b * T_ * U_;
    const bool wr = (vc == 0);

    if (wr) albuf[0][u] = potb[u];        // t = 0 (bias + left included)
    __syncthreads();

    float pc = potb[U_ + u];              // pot[1][u]

    for (int t = 1; t < T_; ++t) {
        const int tn = (t + 1 < T_) ? (t + 1) : (T_ - 1);
        const float pn = potb[(size_t)tn * U_ + u];

        const float4* a4 = reinterpret_cast<const float4*>(albuf[(t - 1) & 1]);
        float s[16];
#pragma unroll
        for (int q = 0; q < 4; ++q) {
            const float4 av = a4[vc * 4 + q];
            s[q * 4 + 0] = (av.x + chain_r[q * 4 + 0]) + pc;
            s[q * 4 + 1] = (av.y + chain_r[q * 4 + 1]) + pc;
            s[q * 4 + 2] = (av.z + chain_r[q * 4 + 2]) + pc;
            s[q * 4 + 3] = (av.w + chain_r[q * 4 + 3]) + pc;
        }
        // tournament 16 -> 1: strict >, left (smaller v) wins ties
        float tv[8]; int ti[8];
#pragma unroll
        for (int i = 0; i < 8; ++i) {
            const bool gt = s[2 * i + 1] > s[2 * i];
            tv[i] = gt ? s[2 * i + 1] : s[2 * i];
            ti[i] = gt ? 2 * i + 1 : 2 * i;
        }
        float uv[4]; int ui[4];
#pragma unroll
        for (int i = 0; i < 4; ++i) {
            const bool gt = tv[2 * i + 1] > tv[2 * i];
            uv[i] = gt ? tv[2 * i + 1] : tv[2 * i];
            ui[i] = gt ? ti[2 * i + 1] : ti[2 * i];
        }
        const bool g0 = uv[1] > uv[0];
        const float w0 = g0 ? uv[1] : uv[0];
        const int   i0 = g0 ? ui[1] : ui[0];
        const bool g1 = uv[3] > uv[2];
        const float w1 = g1 ? uv[3] : uv[2];
        const int   i1 = g1 ? ui[3] : ui[2];
        const bool gf = w1 > w0;
        float bv = gf ? w1 : w0;
        int   gi = vc * 16 + (gf ? i1 : i0);   // global v index

        // butterfly across the 4 v-chunks (adjacent lanes), lex (val, idx):
        // larger val wins; on equal val, smaller v wins  == first occurrence
        {
            const float ov = __shfl_xor(bv, 1);
            const int   oi = __shfl_xor(gi, 1);
            if (ov > bv || (ov == bv && oi < gi)) { bv = ov; gi = oi; }
        }
        {
            const float ov = __shfl_xor(bv, 2);
            const int   oi = __shfl_xor(gi, 2);
            if (ov > bv || (ov == bv && oi < gi)) { bv = ov; gi = oi; }
        }

        if (wr) {
            albuf[t & 1][u] = bv;
            bp[t - 1][u] = (unsigned char)gi;
        }
        __syncthreads();
        pc = pn;
    }

    // ---- backtrace ----
    // segment of wave wv: rows [r0c, r1c)
    const int r0c = wv * 128;
    const int r1c = (wv == 3) ? (T_ - 1) : (wv + 1) * 128;

    // pass 1: composed map of my segment from every possible start tag
    {
        int tag = lane;
        for (int r = r1c - 1; r >= r0c; --r) tag = bp[r][tag];
        cmap[wv][lane] = (unsigned char)tag;
    }
    __syncthreads();

    if (tid == 0) {
        // final argmax over alpha (first occurrence); last write was buf[1]
        const float* af = albuf[(T_ - 1) & 1];
        float bvv = af[0];
        int bii = 0;
        for (int v = 1; v < 64; ++v) {
            const float a = af[v];
            if (a > bvv) { bvv = a; bii = v; }
        }
        path[(size_t)b * T_ + (T_ - 1)] = bii;
        const int e3 = bii;                 // tag_511
        const int e2 = cmap[3][e3];         // tag_384
        const int e1 = cmap[2][e2];         // tag_256
        const int e0 = cmap[1][e1];         // tag_128
        es[0] = e0; es[1] = e1; es[2] = e2; es[3] = e3;
    }
    __syncthreads();

    // pass 2: 4 parallel chases over disjoint row ranges (exact replica of
    // the sequential loop: tag_r = bp[r][tag_{r+1}], path[r] = tag_r)
    if (lane == 0) {
        int tag = es[wv];                   // tag at row r1c (wv==3: tag_511)
        int* pb = path + (size_t)b * T_;
        for (int r = r1c - 1; r >= r0c; --r) {
            tag = bp[r][tag];
            pb[r] = tag;
        }
    }
}

extern "C" void kernel_launch(void* const* d_in, const int* in_sizes, int n_in,
                              void* d_out, int out_size, void* d_ws, size_t ws_size,
                              hipStream_t stream) {
    const float* x  = (const float*)d_in[0];
    const float* w  = (const float*)d_in[1];
    const float* bs = (const float*)d_in[2];
    const float* ck = (const float*)d_in[3];
    const float* lb = (const float*)d_in[4];
    const float* rb = (const float*)d_in[5];

    float* pot = (float*)d_ws;          // [B*T][U] f32 = 8.39 MB
    int* path  = (int*)d_out;           // [B][T] int32

    crf_gemm_kernel<<<dim3(B_ * T_ / 32), dim3(256), 0, stream>>>(x, w, bs, lb, rb, pot);
    crf_viterbi_kernel<<<dim3(B_), dim3(256), 0, stream>>>(pot, ck, path);
}